// Round 1
// baseline (419.289 us; speedup 1.0000x reference)
//
#include <hip/hip_runtime.h>
#include <hip/hip_bf16.h>
#include <cstdint>

#define TPB 256

// ---------------------------------------------------------------------------
// Bias init: out buffers are accumulated into with atomics, so they must be
// (re)initialized to the bias every call (harness does not re-poison).
// ---------------------------------------------------------------------------
struct InitSegs {
    float*       dst[15];
    const float* bias[15];
    int          n[15];
    int          rep[15];
    int          nseg;
};

__global__ __launch_bounds__(TPB) void init_bias_kernel(InitSegs s) {
    int seg = blockIdx.y;
    if (seg >= s.nseg) return;
    float*       d = s.dst[seg];
    const float* b = s.bias[seg];
    int n = s.n[seg];
    int total = n * s.rep[seg];
    for (int i = blockIdx.x * TPB + threadIdx.x; i < total; i += gridDim.x * TPB)
        d[i] = b[i % n];
}

// ---------------------------------------------------------------------------
// Front end: blocks 0..7 = per-face FRC conv/mlp + kernel-correlation + feat
// assembly; blocks 8..9 = sp1 GEMV (24 -> 512), bias included, no relu stored.
// ---------------------------------------------------------------------------
__global__ __launch_bounds__(TPB) void front_kernel(
    const float* __restrict__ center, const float* __restrict__ corner,
    const float* __restrict__ normal,
    const float* __restrict__ spW1, const float* __restrict__ spb1,
    const float* __restrict__ Wc, const float* __restrict__ bc,
    const float* __restrict__ W3, const float* __restrict__ b3,
    const float* __restrict__ W4, const float* __restrict__ b4,
    const float* __restrict__ kck,
    float* __restrict__ T1, float* __restrict__ FEAT) {
    int tid = threadIdx.x;
    if (blockIdx.x < 8) {
        int f = blockIdx.x;
        __shared__ float sc[9], sn[3], sm[32], sh[64];
        if (tid < 9) sc[tid] = corner[f * 9 + tid];
        if (tid < 3) sn[tid] = normal[f * 3 + tid];
        __syncthreads();
        if (tid < 32) {                       // conv over 3 corner pairs, mean
            float acc = 0.f;
            for (int p = 0; p < 3; ++p) {
                const float* a  = &sc[3 * p];
                const float* b2 = &sc[3 * ((p + 1) % 3)];
                float d = bc[tid];
                for (int k = 0; k < 3; ++k)
                    d += a[k] * Wc[tid * 6 + k] + b2[k] * Wc[tid * 6 + 3 + k];
                acc += d;
            }
            sm[tid] = acc * (1.f / 3.f);
        }
        __syncthreads();
        if (tid < 64) {                       // frc hidden (32 -> 64), relu
            float h = b3[tid];
            for (int o = 0; o < 32; ++o) h = fmaf(sm[o], W3[o * 64 + tid], h);
            sh[tid] = fmaxf(h, 0.f);
        }
        __syncthreads();
        if (tid < 64) {                       // frc out (64 -> 64)
            float v = b4[tid];
            for (int k = 0; k < 64; ++k) v = fmaf(sh[k], W4[k * 64 + tid], v);
            FEAT[f * 131 + 67 + tid] = v;
        }
        if (tid < 64) {                       // kernel correlation
            float s = 0.f;
            for (int l = 0; l < 4; ++l) {
                float dx = sn[0] - kck[(tid * 4 + l) * 3 + 0];
                float dy = sn[1] - kck[(tid * 4 + l) * 3 + 1];
                float dz = sn[2] - kck[(tid * 4 + l) * 3 + 2];
                s += expf(-(dx * dx + dy * dy + dz * dz));
            }
            FEAT[f * 131 + 3 + tid] = s * (1.f / 32.f);
        }
        if (tid < 3) FEAT[f * 131 + tid] = sn[tid];
    } else {
        __shared__ float sx[24];
        if (tid < 24) sx[tid] = center[tid];
        __syncthreads();
        int j = (blockIdx.x - 8) * TPB + tid;
        if (j < 512) {
            float a = spb1[j];
            for (int i = 0; i < 24; ++i) a = fmaf(sx[i], spW1[i * 512 + j], a);
            T1[j] = a;
        }
    }
}

// ---------------------------------------------------------------------------
// Structural descriptor: per-face 131 -> 131 (relu) -> 131, shared weights.
// One block per face.
// ---------------------------------------------------------------------------
__global__ __launch_bounds__(TPB) void st_kernel(
    const float* __restrict__ FEAT,
    const float* __restrict__ W1, const float* __restrict__ b1,
    const float* __restrict__ W2, const float* __restrict__ b2,
    float* __restrict__ Z) {
    int f = blockIdx.x, tid = threadIdx.x;
    __shared__ float sf[131], sh[131];
    if (tid < 131) sf[tid] = FEAT[f * 131 + tid];
    __syncthreads();
    if (tid < 131) {
        float a = b1[tid];
        for (int k = 0; k < 131; ++k) a = fmaf(sf[k], W1[k * 131 + tid], a);
        sh[tid] = fmaxf(a, 0.f);
    }
    __syncthreads();
    if (tid < 131) {
        float a = b2[tid];
        for (int k = 0; k < 131; ++k) a = fmaf(sh[k], W2[k * 131 + tid], a);
        Z[f * 131 + tid] = a;
    }
}

// ---------------------------------------------------------------------------
// Generic split-K GEMV:  out[j] (+)= sum_i x[i] * W[i, j]   (W row-major in x out)
// grid.x = column tiles (1024 cols each), grid.y = K chunks, grid.z = batch.
// x chunk staged in LDS (relu folded), W streamed as float4 per lane,
// partials accumulated with HW f32 atomics onto bias-initialized out.
// ---------------------------------------------------------------------------
template <bool RELU_IN>
__global__ __launch_bounds__(TPB) void gemv_kernel(
    const float* __restrict__ x, int x_stride,
    const float* __restrict__ W,
    float* __restrict__ out, int out_stride,
    int in_dim, int out_dim, int chunk) {
    __shared__ float sx[128];
    x   += (size_t)blockIdx.z * x_stride;
    out += (size_t)blockIdx.z * out_stride;
    int row0 = blockIdx.y * chunk;
    int rows = min(chunk, in_dim - row0);
    for (int r = threadIdx.x; r < rows; r += TPB) {
        float v = x[row0 + r];
        sx[r] = RELU_IN ? fmaxf(v, 0.f) : v;
    }
    __syncthreads();
    int j = blockIdx.x * (TPB * 4) + threadIdx.x * 4;
    if (j >= out_dim) return;
    const float* wp = W + (size_t)row0 * out_dim + j;
    float ax = 0.f, ay = 0.f, az = 0.f, aw = 0.f;
#pragma unroll 4
    for (int r = 0; r < rows; ++r) {
        float4 w4 = *reinterpret_cast<const float4*>(wp);
        float xv = sx[r];
        ax = fmaf(xv, w4.x, ax);
        ay = fmaf(xv, w4.y, ay);
        az = fmaf(xv, w4.z, az);
        aw = fmaf(xv, w4.w, aw);
        wp += out_dim;
    }
    unsafeAtomicAdd(&out[j + 0], ax);
    unsafeAtomicAdd(&out[j + 1], ay);
    unsafeAtomicAdd(&out[j + 2], az);
    unsafeAtomicAdd(&out[j + 3], aw);
}

// ---------------------------------------------------------------------------
// Neighbour aggregation: out[i,k] = (z[i,k] + sum_{j<3} z[nb[i,j],k]) / 4
// ---------------------------------------------------------------------------
__global__ __launch_bounds__(TPB) void agg_kernel(
    const float* __restrict__ z, const int* __restrict__ nb,
    float* __restrict__ out, int dim) {
    int idx = blockIdx.x * TPB + threadIdx.x;
    if (idx >= 8 * dim) return;
    int i = idx / dim, k = idx - i * dim;
    int n0 = nb[i * 3 + 0], n1 = nb[i * 3 + 1], n2 = nb[i * 3 + 2];
    out[idx] = 0.25f * (z[i * dim + k] + z[n0 * dim + k] + z[n1 * dim + k] + z[n2 * dim + k]);
}

// out6 tail: out6 = [out5 (8192, written in place) | out3 (4096) | out1 (2048)]
__global__ __launch_bounds__(TPB) void copy6_kernel(
    const float* __restrict__ out34, const float* __restrict__ out12,
    float* __restrict__ out6) {
    int i = blockIdx.x * TPB + threadIdx.x;
    if (i < 4096) out6[8192 + i] = out34[i];
    else if (i < 6144) out6[12288 + (i - 4096)] = out12[i - 4096];
}

__global__ __launch_bounds__(TPB) void maxpool_kernel(
    const float* __restrict__ h, float* __restrict__ g) {
    int j = blockIdx.x * TPB + threadIdx.x;
    if (j >= 1024) return;
    float m = h[j];
    for (int f = 1; f < 8; ++f) m = fmaxf(m, h[f * 1024 + j]);
    g[j] = m;
}

// final 256 -> 40 with relu on input
__global__ __launch_bounds__(64) void head_kernel(
    const float* __restrict__ x, const float* __restrict__ W,
    const float* __restrict__ b, float* __restrict__ out) {
    __shared__ float sx[256];
    int tid = threadIdx.x;
    for (int k = tid; k < 256; k += 64) sx[k] = fmaxf(x[k], 0.f);
    __syncthreads();
    if (tid < 40) {
        float a = b[tid];
        for (int k = 0; k < 256; ++k) a = fmaf(sx[k], W[k * 40 + tid], a);
        out[tid] = a;
    }
}

// ---------------------------------------------------------------------------
static inline void gemv(hipStream_t s, const float* x, const float* W, float* out,
                        int in_dim, int out_dim, int chunk, bool relu_in,
                        int nvec = 1, int x_stride = 0, int out_stride = 0) {
    dim3 grid((out_dim + TPB * 4 - 1) / (TPB * 4), (in_dim + chunk - 1) / chunk, nvec);
    if (relu_in)
        gemv_kernel<true><<<grid, TPB, 0, s>>>(x, x_stride, W, out, out_stride, in_dim, out_dim, chunk);
    else
        gemv_kernel<false><<<grid, TPB, 0, s>>>(x, x_stride, W, out, out_stride, in_dim, out_dim, chunk);
}

extern "C" void kernel_launch(void* const* d_in, const int* in_sizes, int n_in,
                              void* d_out, int out_size, void* d_ws, size_t ws_size,
                              hipStream_t stream) {
    const float* center    = (const float*)d_in[0];
    const float* corner    = (const float*)d_in[1];
    const float* normal    = (const float*)d_in[2];
    const int*   neighbour = (const int*)  d_in[3];
    const float* sp_W1 = (const float*)d_in[4];
    const float* sp_b1 = (const float*)d_in[5];
    const float* sp_W2 = (const float*)d_in[6];
    const float* sp_b2 = (const float*)d_in[7];
    const float* frc_Wc = (const float*)d_in[8];
    const float* frc_bc = (const float*)d_in[9];
    const float* frc_W3 = (const float*)d_in[10];
    const float* frc_b3 = (const float*)d_in[11];
    const float* frc_W4 = (const float*)d_in[12];
    const float* frc_b4 = (const float*)d_in[13];
    const float* kc_kernel = (const float*)d_in[14];
    const float* st_W1 = (const float*)d_in[15];
    const float* st_b1 = (const float*)d_in[16];
    const float* st_W2 = (const float*)d_in[17];
    const float* st_b2 = (const float*)d_in[18];
    const float* c1_W1 = (const float*)d_in[19];
    const float* c1_b1 = (const float*)d_in[20];
    const float* c1_W2 = (const float*)d_in[21];
    const float* c1_b2 = (const float*)d_in[22];
    const float* a1_W3 = (const float*)d_in[23];
    const float* a1_b3 = (const float*)d_in[24];
    const float* a1_W4 = (const float*)d_in[25];
    const float* a1_b4 = (const float*)d_in[26];
    const float* c2_W1 = (const float*)d_in[27];
    const float* c2_b1 = (const float*)d_in[28];
    const float* c2_W2 = (const float*)d_in[29];
    const float* c2_b2 = (const float*)d_in[30];
    const float* a2_W3 = (const float*)d_in[31];
    const float* a2_b3 = (const float*)d_in[32];
    const float* a2_W4 = (const float*)d_in[33];
    const float* a2_b4 = (const float*)d_in[34];
    const float* nt_W1 = (const float*)d_in[35];
    const float* nt_b1 = (const float*)d_in[36];
    const float* nt_W2 = (const float*)d_in[37];
    const float* nt_b2 = (const float*)d_in[38];
    const float* m2_W1 = (const float*)d_in[39];
    const float* m2_b1 = (const float*)d_in[40];
    const float* m2_W2 = (const float*)d_in[41];
    const float* m2_b2 = (const float*)d_in[42];
    const float* m3_W1 = (const float*)d_in[43];
    const float* m3_b1 = (const float*)d_in[44];
    const float* m3_W2 = (const float*)d_in[45];
    const float* m3_b2 = (const float*)d_in[46];
    const float* m3_W3 = (const float*)d_in[47];
    const float* m3_b3 = (const float*)d_in[48];

    float* ws = (float*)d_ws;
    float* T1    = ws;                 // 512
    float* C1IN  = ws + 512;           // 1560  [y | z]
    float* Z     = C1IN + 512;         // 1048  (z region of C1IN)
    float* AGG1  = ws + 2072;          // 1048
    float* C1H   = ws + 3120;          // 1600
    float* OUT12 = ws + 4720;          // 4096  [out1 | out2]
    float* A1H   = ws + 8816;          // 4096
    float* C2H   = ws + 12912;         // 4096
    float* OUT34 = ws + 17008;         // 8192  [out3 | out4]
    float* AGG2  = ws + 25200;         // 2048
    float* A2H   = ws + 27248;         // 4096
    float* NTH   = ws + 31344;         // 8192
    float* OUT6  = ws + 39536;         // 14336 [out5 | out3 | out1]
    float* M2H   = ws + 53872;         // 8192
    float* HBUF  = ws + 62064;         // 8192
    float* G     = ws + 70256;         // 1024
    float* M3H1  = ws + 71280;         // 512
    float* M3H2  = ws + 71792;         // 256
    float* FEAT  = ws + 72048;         // 1048

    InitSegs s{};
    int k = 0;
    auto add = [&](float* d, const float* b, int n, int rep) {
        s.dst[k] = d; s.bias[k] = b; s.n[k] = n; s.rep[k] = rep; ++k;
    };
    add(C1IN,         sp_b2, 512, 1);
    add(C1H,          c1_b1, 1600, 1);
    add(OUT12,        c1_b2, 2048, 1);
    add(A1H,          a1_b3, 4096, 1);
    add(OUT12 + 2048, a1_b4, 2048, 1);
    add(C2H,          c2_b1, 4096, 1);
    add(OUT34,        c2_b2, 4096, 1);
    add(A2H,          a2_b3, 4096, 1);
    add(OUT34 + 4096, a2_b4, 4096, 1);
    add(NTH,          nt_b1, 1024, 8);
    add(OUT6,         nt_b2, 1024, 8);
    add(M2H,          m2_b1, 8192, 1);
    add(HBUF,         m2_b2, 8192, 1);
    add(M3H1,         m3_b1, 512, 1);
    add(M3H2,         m3_b2, 256, 1);
    s.nseg = k;
    init_bias_kernel<<<dim3(32, 15), TPB, 0, stream>>>(s);

    front_kernel<<<10, TPB, 0, stream>>>(center, corner, normal, sp_W1, sp_b1,
                                         frc_Wc, frc_bc, frc_W3, frc_b3, frc_W4, frc_b4,
                                         kc_kernel, T1, FEAT);
    st_kernel<<<8, TPB, 0, stream>>>(FEAT, st_W1, st_b1, st_W2, st_b2, Z);
    agg_kernel<<<(8 * 131 + TPB - 1) / TPB, TPB, 0, stream>>>(Z, neighbour, AGG1, 131);

    gemv(stream, T1, sp_W2, C1IN, 512, 512, 16, true);            // y
    gemv(stream, C1IN, c1_W1, C1H, 1560, 1600, 16, false);
    gemv(stream, C1H, c1_W2, OUT12, 1600, 2048, 16, true);        // out1
    gemv(stream, AGG1, a1_W3, A1H, 1048, 4096, 16, false);
    gemv(stream, A1H, a1_W4, OUT12 + 2048, 4096, 2048, 32, true); // out2
    agg_kernel<<<(2048 + TPB - 1) / TPB, TPB, 0, stream>>>(OUT12 + 2048, neighbour, AGG2, 256);
    gemv(stream, OUT12, c2_W1, C2H, 4096, 4096, 32, false);
    gemv(stream, C2H, c2_W2, OUT34, 4096, 4096, 32, true);        // out3
    gemv(stream, AGG2, a2_W3, A2H, 2048, 4096, 16, false);
    gemv(stream, A2H, a2_W4, OUT34 + 4096, 4096, 4096, 32, true); // out4
    gemv(stream, OUT34, nt_W1, NTH, 1024, 1024, 64, false, 8, 1024, 1024);
    gemv(stream, NTH, nt_W2, OUT6, 1024, 1024, 64, true, 8, 1024, 1024); // out5
    copy6_kernel<<<6144 / TPB, TPB, 0, stream>>>(OUT34, OUT12, OUT6);
    gemv(stream, OUT6, m2_W1, M2H, 14336, 8192, 112, false);
    gemv(stream, M2H, m2_W2, HBUF, 8192, 8192, 128, true);
    maxpool_kernel<<<4, TPB, 0, stream>>>(HBUF, G);
    gemv(stream, G, m3_W1, M3H1, 1024, 512, 32, false);
    gemv(stream, M3H1, m3_W2, M3H2, 512, 256, 32, true);
    head_kernel<<<1, 64, 0, stream>>>(M3H2, m3_W3, m3_b3, (float*)d_out);
}

// Round 2
// 346.049 us; speedup vs baseline: 1.2116x; 1.2116x over previous
//
#include <hip/hip_runtime.h>
#include <cstdint>

#define TPB 256
typedef __attribute__((ext_vector_type(4))) float f4;

// ---------------------------------------------------------------------------
// Workspace layout (floats):
//   Y     @  512 (512)   C1IN = [Y|Z] @ 512 (1560)
//   Z     @ 1024 (1048)
//   C1H   @ 2072 (1600)
//   OUT12 @ 3672 (4096)  [out1 | out2]
//   A1H   @ 7768 (4096)
//   C2H   @11864 (4096)
//   OUT34 @15960 (8192)  [out3 | out4]
//   A2H   @24152 (4096)
//   NTH   @28248 (8192)
//   OUT6  @36440 (14336) [out5 | out3copy | out1copy]
//   M2H   @50776 (8192)
//   HBUF  @58968 (8192)
//   M3H1  @67160 (512)
//   M3H2  @67672 (256)
//   end   @67928
// Zero range (atomic-accumulated buffers): [2072, 67928)
// ---------------------------------------------------------------------------

// ---------------------------------------------------------------------------
// Stage 1: per-face FRC+KC+structural MLP (blocks 0-7), spatial chain
// 24->512->512 (blocks 8-11, full-K, direct write), zero accum region
// (blocks 12-43).
// ---------------------------------------------------------------------------
__global__ __launch_bounds__(TPB) void stage1_kernel(
    const float* __restrict__ center, const float* __restrict__ corner,
    const float* __restrict__ normal,
    const float* __restrict__ spW1, const float* __restrict__ spb1,
    const float* __restrict__ spW2, const float* __restrict__ spb2,
    const float* __restrict__ Wc, const float* __restrict__ bc,
    const float* __restrict__ W3, const float* __restrict__ b3,
    const float* __restrict__ W4, const float* __restrict__ b4,
    const float* __restrict__ kck,
    const float* __restrict__ stW1, const float* __restrict__ stb1,
    const float* __restrict__ stW2, const float* __restrict__ stb2,
    float* __restrict__ ws) {
    int tid = threadIdx.x;
    int b = blockIdx.x;
    if (b < 8) {
        // ---- one face per block: FRC conv+mlp, kernel correlation, st MLP
        int f = b;
        __shared__ float sc[9], sn[3], sm[32], shh[64], sf[131], sh2[131];
        if (tid < 9) sc[tid] = corner[f * 9 + tid];
        if (tid < 3) { sn[tid] = normal[f * 3 + tid]; sf[tid] = normal[f * 3 + tid]; }
        __syncthreads();
        if (tid < 32) {                       // conv over 3 corner pairs, mean
            float acc = 0.f;
            for (int p = 0; p < 3; ++p) {
                const float* a  = &sc[3 * p];
                const float* b2 = &sc[3 * ((p + 1) % 3)];
                float d = bc[tid];
                for (int k = 0; k < 3; ++k)
                    d += a[k] * Wc[tid * 6 + k] + b2[k] * Wc[tid * 6 + 3 + k];
                acc += d;
            }
            sm[tid] = acc * (1.f / 3.f);
        }
        __syncthreads();
        if (tid < 64) {                       // frc hidden (32 -> 64), relu
            float h = b3[tid];
            for (int o = 0; o < 32; ++o) h = fmaf(sm[o], W3[o * 64 + tid], h);
            shh[tid] = fmaxf(h, 0.f);
        }
        if (tid < 64) {                       // kernel correlation -> sf[3+tid]
            float s = 0.f;
            for (int l = 0; l < 4; ++l) {
                float dx = sn[0] - kck[(tid * 4 + l) * 3 + 0];
                float dy = sn[1] - kck[(tid * 4 + l) * 3 + 1];
                float dz = sn[2] - kck[(tid * 4 + l) * 3 + 2];
                s += expf(-(dx * dx + dy * dy + dz * dz));
            }
            sf[3 + tid] = s * (1.f / 32.f);
        }
        __syncthreads();
        if (tid < 64) {                       // frc out (64 -> 64) -> sf[67+tid]
            float v = b4[tid];
            for (int k = 0; k < 64; ++k) v = fmaf(shh[k], W4[k * 64 + tid], v);
            sf[67 + tid] = v;
        }
        __syncthreads();
        if (tid < 131) {                      // st hidden, relu
            float a = stb1[tid];
            for (int k = 0; k < 131; ++k) a = fmaf(sf[k], stW1[k * 131 + tid], a);
            sh2[tid] = fmaxf(a, 0.f);
        }
        __syncthreads();
        if (tid < 131) {                      // st out -> Z
            float a = stb2[tid];
            for (int k = 0; k < 131; ++k) a = fmaf(sh2[k], stW2[k * 131 + tid], a);
            ws[1024 + f * 131 + tid] = a;
        }
    } else if (b < 12) {
        // ---- spatial chain: T1 = relu(center@spW1+b1) in LDS; y = T1@spW2+b2
        int bs = b - 8;
        __shared__ float sctr[24], st1[512];
        if (tid < 24) sctr[tid] = center[tid];
        __syncthreads();
        for (int j = tid; j < 512; j += TPB) {
            float a = spb1[j];
            for (int i = 0; i < 24; ++i) a = fmaf(sctr[i], spW1[i * 512 + j], a);
            st1[j] = fmaxf(a, 0.f);
        }
        __syncthreads();
        if (tid < 128) {
            int j = bs * 128 + tid;
            float a = spb2[j];
            for (int k = 0; k < 512; ++k) a = fmaf(st1[k], spW2[k * 512 + j], a);
            ws[512 + j] = a;                  // Y, direct write
        }
    } else {
        // ---- zero the atomic-accumulated region [2072, 67928)
        int zb = b - 12;                      // 0..31
        f4 z4 = {0.f, 0.f, 0.f, 0.f};
        f4* p = (f4*)(ws + 2072);
        int n4 = (67928 - 2072) / 4;          // 16464
        for (int i = zb * TPB + tid; i < n4; i += 32 * TPB) p[i] = z4;
    }
}

// ---------------------------------------------------------------------------
// Multi-GEMV: up to 3 descriptors per launch. Split-K with HW f32 atomics
// onto zeroed buffers; bias folded into the ci==0 chunk; x-staging fuses
// relu / neighbour-agg / maxpool; op 4 = plain float4 copy.
// ---------------------------------------------------------------------------
struct Desc {
    const float* x; const float* W; float* out; const float* bias;
    const int* nb;
    int in_dim, out_dim, chunk, ntile, nchunk, nvec, xs, os;
    int op;        // 0 direct, 1 relu-in, 2 agg, 3 maxpool8, 4 copy
    int aggdim;
    int cached;    // 1 = cached loads (weight reuse), 0 = nontemporal stream
    int nblocks;
};
struct Descs { Desc d[3]; int nd; };

__global__ __launch_bounds__(TPB) void mg_kernel(Descs D) {
    int bid = blockIdx.x;
    int di = 0;
    while (di + 1 < D.nd && bid >= D.d[di].nblocks) { bid -= D.d[di].nblocks; ++di; }
    Desc d = D.d[di];
    int tid = threadIdx.x;
    if (d.op == 4) {                          // copy
        int i = bid * TPB + tid;
        int n4 = d.in_dim >> 2;
        if (i < n4) ((f4*)d.out)[i] = ((const f4*)d.x)[i];
        return;
    }
    __shared__ float sx[128];
    int per = d.ntile * d.nchunk;
    int vec = bid / per;
    int r = bid - vec * per;
    int ci = r / d.ntile;
    int tile = r - ci * d.ntile;
    const float* x = d.x + (size_t)vec * d.xs;
    float* out = d.out + (size_t)vec * d.os;
    int row0 = ci * d.chunk;
    int rows = min(d.chunk, d.in_dim - row0);
    for (int t = tid; t < rows; t += TPB) {
        int idx = row0 + t;
        float v;
        if (d.op == 2) {
            int i = idx / d.aggdim, k = idx - i * d.aggdim;
            const int* nb = d.nb + i * 3;
            v = 0.25f * (x[i * d.aggdim + k] + x[nb[0] * d.aggdim + k] +
                         x[nb[1] * d.aggdim + k] + x[nb[2] * d.aggdim + k]);
        } else if (d.op == 3) {
            v = x[idx];
#pragma unroll
            for (int f = 1; f < 8; ++f) v = fmaxf(v, x[f * d.in_dim + idx]);
        } else {
            v = x[idx];
            if (d.op == 1) v = fmaxf(v, 0.f);
        }
        sx[t] = v;
    }
    __syncthreads();
    int j = tile * (TPB * 4) + tid * 4;
    if (j >= d.out_dim) return;
    const float* wp = d.W + (size_t)row0 * d.out_dim + j;
    float ax = 0.f, ay = 0.f, az = 0.f, aw = 0.f;
    if (d.cached) {
#pragma unroll 8
        for (int t = 0; t < rows; ++t) {
            f4 w = *(const f4*)wp;
            float xv = sx[t];
            ax = fmaf(xv, w[0], ax); ay = fmaf(xv, w[1], ay);
            az = fmaf(xv, w[2], az); aw = fmaf(xv, w[3], aw);
            wp += d.out_dim;
        }
    } else {
#pragma unroll 8
        for (int t = 0; t < rows; ++t) {
            f4 w = __builtin_nontemporal_load((const f4*)wp);
            float xv = sx[t];
            ax = fmaf(xv, w[0], ax); ay = fmaf(xv, w[1], ay);
            az = fmaf(xv, w[2], az); aw = fmaf(xv, w[3], aw);
            wp += d.out_dim;
        }
    }
    if (ci == 0 && d.bias) {
        ax += d.bias[j]; ay += d.bias[j + 1]; az += d.bias[j + 2]; aw += d.bias[j + 3];
    }
    unsafeAtomicAdd(&out[j + 0], ax);
    unsafeAtomicAdd(&out[j + 1], ay);
    unsafeAtomicAdd(&out[j + 2], az);
    unsafeAtomicAdd(&out[j + 3], aw);
}

// head: logits = relu(M3H2) @ m3_W3 + b3   (256 -> 40)
__global__ __launch_bounds__(64) void head_kernel(
    const float* __restrict__ x, const float* __restrict__ W,
    const float* __restrict__ b, float* __restrict__ out) {
    __shared__ float sx[256];
    int tid = threadIdx.x;
    for (int k = tid; k < 256; k += 64) sx[k] = fmaxf(x[k], 0.f);
    __syncthreads();
    if (tid < 40) {
        float a = b[tid];
        for (int k = 0; k < 256; ++k) a = fmaf(sx[k], W[k * 40 + tid], a);
        out[tid] = a;
    }
}

// ---------------------------------------------------------------------------
static Desc gemv_desc(const float* x, const float* W, float* out, const float* bias,
                      int in, int outd, int chunk, int op, int cached = 0,
                      int nvec = 1, int xs = 0, int os = 0,
                      const int* nb = nullptr, int aggdim = 0) {
    Desc d{};
    d.x = x; d.W = W; d.out = out; d.bias = bias; d.nb = nb;
    d.in_dim = in; d.out_dim = outd; d.chunk = chunk;
    d.ntile = (outd + TPB * 4 - 1) / (TPB * 4);
    d.nchunk = (in + chunk - 1) / chunk;
    d.nvec = nvec; d.xs = xs; d.os = os;
    d.op = op; d.aggdim = aggdim; d.cached = cached;
    d.nblocks = d.ntile * d.nchunk * nvec;
    return d;
}
static Desc copy_desc(const float* src, float* dst, int n) {
    Desc d{};
    d.x = src; d.out = dst; d.in_dim = n; d.op = 4;
    d.nblocks = (n / 4 + TPB - 1) / TPB;
    return d;
}
static void mg1(hipStream_t s, Desc a) {
    Descs D{}; D.d[0] = a; D.nd = 1;
    mg_kernel<<<a.nblocks, TPB, 0, s>>>(D);
}
static void mg2(hipStream_t s, Desc a, Desc b) {
    Descs D{}; D.d[0] = a; D.d[1] = b; D.nd = 2;
    mg_kernel<<<a.nblocks + b.nblocks, TPB, 0, s>>>(D);
}
static void mg3(hipStream_t s, Desc a, Desc b, Desc c) {
    Descs D{}; D.d[0] = a; D.d[1] = b; D.d[2] = c; D.nd = 3;
    mg_kernel<<<a.nblocks + b.nblocks + c.nblocks, TPB, 0, s>>>(D);
}

extern "C" void kernel_launch(void* const* d_in, const int* in_sizes, int n_in,
                              void* d_out, int out_size, void* d_ws, size_t ws_size,
                              hipStream_t stream) {
    const float* center    = (const float*)d_in[0];
    const float* corner    = (const float*)d_in[1];
    const float* normal    = (const float*)d_in[2];
    const int*   neighbour = (const int*)  d_in[3];
    const float* sp_W1 = (const float*)d_in[4];
    const float* sp_b1 = (const float*)d_in[5];
    const float* sp_W2 = (const float*)d_in[6];
    const float* sp_b2 = (const float*)d_in[7];
    const float* frc_Wc = (const float*)d_in[8];
    const float* frc_bc = (const float*)d_in[9];
    const float* frc_W3 = (const float*)d_in[10];
    const float* frc_b3 = (const float*)d_in[11];
    const float* frc_W4 = (const float*)d_in[12];
    const float* frc_b4 = (const float*)d_in[13];
    const float* kc_kernel = (const float*)d_in[14];
    const float* st_W1 = (const float*)d_in[15];
    const float* st_b1 = (const float*)d_in[16];
    const float* st_W2 = (const float*)d_in[17];
    const float* st_b2 = (const float*)d_in[18];
    const float* c1_W1 = (const float*)d_in[19];
    const float* c1_b1 = (const float*)d_in[20];
    const float* c1_W2 = (const float*)d_in[21];
    const float* c1_b2 = (const float*)d_in[22];
    const float* a1_W3 = (const float*)d_in[23];
    const float* a1_b3 = (const float*)d_in[24];
    const float* a1_W4 = (const float*)d_in[25];
    const float* a1_b4 = (const float*)d_in[26];
    const float* c2_W1 = (const float*)d_in[27];
    const float* c2_b1 = (const float*)d_in[28];
    const float* c2_W2 = (const float*)d_in[29];
    const float* c2_b2 = (const float*)d_in[30];
    const float* a2_W3 = (const float*)d_in[31];
    const float* a2_b3 = (const float*)d_in[32];
    const float* a2_W4 = (const float*)d_in[33];
    const float* a2_b4 = (const float*)d_in[34];
    const float* nt_W1 = (const float*)d_in[35];
    const float* nt_b1 = (const float*)d_in[36];
    const float* nt_W2 = (const float*)d_in[37];
    const float* nt_b2 = (const float*)d_in[38];
    const float* m2_W1 = (const float*)d_in[39];
    const float* m2_b1 = (const float*)d_in[40];
    const float* m2_W2 = (const float*)d_in[41];
    const float* m2_b2 = (const float*)d_in[42];
    const float* m3_W1 = (const float*)d_in[43];
    const float* m3_b1 = (const float*)d_in[44];
    const float* m3_W2 = (const float*)d_in[45];
    const float* m3_b2 = (const float*)d_in[46];
    const float* m3_W3 = (const float*)d_in[47];
    const float* m3_b3 = (const float*)d_in[48];

    float* ws = (float*)d_ws;
    float* C1IN  = ws + 512;           // [Y(512) | Z(1048)]
    float* Z     = ws + 1024;
    float* C1H   = ws + 2072;
    float* OUT12 = ws + 3672;          // [out1 | out2]
    float* A1H   = ws + 7768;
    float* C2H   = ws + 11864;
    float* OUT34 = ws + 15960;         // [out3 | out4]
    float* A2H   = ws + 24152;
    float* NTH   = ws + 28248;
    float* OUT6  = ws + 36440;         // [out5 | out3c | out1c]
    float* M2H   = ws + 50776;
    float* HBUF  = ws + 58968;
    float* M3H1  = ws + 67160;
    float* M3H2  = ws + 67672;

    // L1: faces + spatial chain + zeroing
    stage1_kernel<<<44, TPB, 0, stream>>>(center, corner, normal,
        sp_W1, sp_b1, sp_W2, sp_b2, frc_Wc, frc_bc, frc_W3, frc_b3,
        frc_W4, frc_b4, kc_kernel, st_W1, st_b1, st_W2, st_b2, ws);

    // L2: c1_W1 (x=[y|z]) + a1_W3 (agg1 inline from Z)
    mg2(stream,
        gemv_desc(C1IN, c1_W1, C1H, c1_b1, 1560, 1600, 16, 0),
        gemv_desc(Z, a1_W3, A1H, a1_b3, 1048, 4096, 16, 2, 0, 1, 0, 0, neighbour, 131));
    // L3: c1_W2 + a1_W4
    mg2(stream,
        gemv_desc(C1H, c1_W2, OUT12, c1_b2, 1600, 2048, 32, 1),
        gemv_desc(A1H, a1_W4, OUT12 + 2048, a1_b4, 4096, 2048, 32, 1));
    // L4: c2_W1 + a2_W3 (agg2 inline from out2)
    mg2(stream,
        gemv_desc(OUT12, c2_W1, C2H, c2_b1, 4096, 4096, 32, 0),
        gemv_desc(OUT12 + 2048, a2_W3, A2H, a2_b3, 2048, 4096, 16, 2, 0, 1, 0, 0, neighbour, 256));
    // L5: c2_W2 + a2_W4 + copy out1 -> OUT6 tail
    mg3(stream,
        gemv_desc(C2H, c2_W2, OUT34, c2_b2, 4096, 4096, 32, 1),
        gemv_desc(A2H, a2_W4, OUT34 + 4096, a2_b4, 4096, 4096, 32, 1),
        copy_desc(OUT12, OUT6 + 12288, 2048));
    // L6: nt_W1 (8 faces) + copy out3 -> OUT6 mid
    mg2(stream,
        gemv_desc(OUT34, nt_W1, NTH, nt_b1, 1024, 1024, 64, 0, 1, 8, 1024, 1024),
        copy_desc(OUT34, OUT6 + 8192, 4096));
    // L7: nt_W2 -> out5
    mg1(stream,
        gemv_desc(NTH, nt_W2, OUT6, nt_b2, 1024, 1024, 64, 1, 1, 8, 1024, 1024));
    // L8: m2_W1
    mg1(stream, gemv_desc(OUT6, m2_W1, M2H, m2_b1, 14336, 8192, 112, 0));
    // L9: m2_W2
    mg1(stream, gemv_desc(M2H, m2_W2, HBUF, m2_b2, 8192, 8192, 64, 1));
    // L10: m3_W1 with inline maxpool over 8 faces
    mg1(stream, gemv_desc(HBUF, m3_W1, M3H1, m3_b1, 1024, 512, 32, 3));
    // L11: m3_W2
    mg1(stream, gemv_desc(M3H1, m3_W2, M3H2, m3_b2, 512, 256, 32, 1));
    // L12: head
    head_kernel<<<1, 64, 0, stream>>>(M3H2, m3_W3, m3_b3, (float*)d_out);
}

// Round 3
// 338.018 us; speedup vs baseline: 1.2404x; 1.0238x over previous
//
#include <hip/hip_runtime.h>
#include <cstdint>

#define TPB 256
typedef __attribute__((ext_vector_type(4))) float f4;

// ---------------------------------------------------------------------------
// Workspace layout (floats):
//   Y     @  512 (512)   C1IN = [Y|Z] @ 512 (1560)
//   Z     @ 1024 (1048)
//   C1H   @ 2072 (1600)
//   OUT12 @ 3672 (4096)  [out1 | out2]
//   A1H   @ 7768 (4096)
//   C2H   @11864 (4096)
//   OUT34 @15960 (8192)  [out3 | out4]
//   A2H   @24152 (4096)
//   NTH   @28248 (8192)
//   OUT6  @36440 (14336) [out5 | out3copy | out1copy]
//   M2H   @50776 (8192)
//   HBUF  @58968 (8192)
//   M3H1  @67160 (512)
//   M3H2  @67672 (256)
//   end   @67928
// Zero range (atomic-accumulated buffers): [2072, 67928)
// ---------------------------------------------------------------------------

__global__ __launch_bounds__(TPB) void stage1_kernel(
    const float* __restrict__ center, const float* __restrict__ corner,
    const float* __restrict__ normal,
    const float* __restrict__ spW1, const float* __restrict__ spb1,
    const float* __restrict__ spW2, const float* __restrict__ spb2,
    const float* __restrict__ Wc, const float* __restrict__ bc,
    const float* __restrict__ W3, const float* __restrict__ b3,
    const float* __restrict__ W4, const float* __restrict__ b4,
    const float* __restrict__ kck,
    const float* __restrict__ stW1, const float* __restrict__ stb1,
    const float* __restrict__ stW2, const float* __restrict__ stb2,
    float* __restrict__ ws) {
    int tid = threadIdx.x;
    int b = blockIdx.x;
    if (b < 8) {
        // ---- one face per block: FRC conv+mlp, kernel correlation, st MLP
        int f = b;
        __shared__ float sc[9], sn[3], sm[32], shh[64], sf[131], sh2[131];
        if (tid < 9) sc[tid] = corner[f * 9 + tid];
        if (tid < 3) { sn[tid] = normal[f * 3 + tid]; sf[tid] = normal[f * 3 + tid]; }
        __syncthreads();
        if (tid < 32) {                       // conv over 3 corner pairs, mean
            float acc = 0.f;
            for (int p = 0; p < 3; ++p) {
                const float* a  = &sc[3 * p];
                const float* b2 = &sc[3 * ((p + 1) % 3)];
                float d = bc[tid];
                for (int k = 0; k < 3; ++k)
                    d += a[k] * Wc[tid * 6 + k] + b2[k] * Wc[tid * 6 + 3 + k];
                acc += d;
            }
            sm[tid] = acc * (1.f / 3.f);
        }
        __syncthreads();
        if (tid < 64) {                       // frc hidden (32 -> 64), relu
            float h = b3[tid];
            for (int o = 0; o < 32; ++o) h = fmaf(sm[o], W3[o * 64 + tid], h);
            shh[tid] = fmaxf(h, 0.f);
        }
        if (tid < 64) {                       // kernel correlation -> sf[3+tid]
            float s = 0.f;
            for (int l = 0; l < 4; ++l) {
                float dx = sn[0] - kck[(tid * 4 + l) * 3 + 0];
                float dy = sn[1] - kck[(tid * 4 + l) * 3 + 1];
                float dz = sn[2] - kck[(tid * 4 + l) * 3 + 2];
                s += expf(-(dx * dx + dy * dy + dz * dz));
            }
            sf[3 + tid] = s * (1.f / 32.f);
        }
        __syncthreads();
        if (tid < 64) {                       // frc out (64 -> 64) -> sf[67+tid]
            float v = b4[tid];
            for (int k = 0; k < 64; ++k) v = fmaf(shh[k], W4[k * 64 + tid], v);
            sf[67 + tid] = v;
        }
        __syncthreads();
        if (tid < 131) {                      // st hidden, relu
            float a = stb1[tid];
            for (int k = 0; k < 131; ++k) a = fmaf(sf[k], stW1[k * 131 + tid], a);
            sh2[tid] = fmaxf(a, 0.f);
        }
        __syncthreads();
        if (tid < 131) {                      // st out -> Z
            float a = stb2[tid];
            for (int k = 0; k < 131; ++k) a = fmaf(sh2[k], stW2[k * 131 + tid], a);
            ws[1024 + f * 131 + tid] = a;
        }
    } else if (b < 12) {
        // ---- spatial chain: T1 = relu(center@spW1+b1) in LDS; y = T1@spW2+b2
        int bs = b - 8;
        __shared__ float sctr[24], st1[512];
        if (tid < 24) sctr[tid] = center[tid];
        __syncthreads();
        for (int j = tid; j < 512; j += TPB) {
            float a = spb1[j];
            for (int i = 0; i < 24; ++i) a = fmaf(sctr[i], spW1[i * 512 + j], a);
            st1[j] = fmaxf(a, 0.f);
        }
        __syncthreads();
        if (tid < 128) {
            int j = bs * 128 + tid;
            float a = spb2[j];
            for (int k = 0; k < 512; ++k) a = fmaf(st1[k], spW2[k * 512 + j], a);
            ws[512 + j] = a;                  // Y, direct write
        }
    } else {
        // ---- zero the atomic-accumulated region [2072, 67928)
        int zb = b - 12;                      // 0..31
        f4 z4 = {0.f, 0.f, 0.f, 0.f};
        f4* p = (f4*)(ws + 2072);
        int n4 = (67928 - 2072) / 4;          // 16464
        for (int i = zb * TPB + tid; i < n4; i += 32 * TPB) p[i] = z4;
    }
}

// ---------------------------------------------------------------------------
// Multi-GEMV: up to 3 descriptors per launch. Split-K with HW f32 atomics
// onto zeroed buffers; bias folded into the ci==0 chunk; x-staging fuses
// relu / neighbour-agg / maxpool; op 4 = plain float4 copy.
// ---------------------------------------------------------------------------
struct Desc {
    const float* x; const float* W; float* out; const float* bias;
    const int* nb;
    int in_dim, out_dim, chunk, ntile, nchunk, nvec, xs, os;
    int op;        // 0 direct, 1 relu-in, 2 agg, 3 maxpool8, 4 copy
    int aggdim;
    int nblocks;
};
struct Descs { Desc d[3]; int nd; };

__global__ __launch_bounds__(TPB) void mg_kernel(Descs D) {
    int bid = blockIdx.x;
    int di = 0;
    while (di + 1 < D.nd && bid >= D.d[di].nblocks) { bid -= D.d[di].nblocks; ++di; }
    Desc d = D.d[di];
    int tid = threadIdx.x;
    if (d.op == 4) {                          // copy
        int i = bid * TPB + tid;
        int n4 = d.in_dim >> 2;
        if (i < n4) ((f4*)d.out)[i] = ((const f4*)d.x)[i];
        return;
    }
    __shared__ float sx[512];
    int per = d.ntile * d.nchunk;
    int vec = bid / per;
    int r = bid - vec * per;
    int ci = r / d.ntile;
    int tile = r - ci * d.ntile;
    const float* x = d.x + (size_t)vec * d.xs;
    float* out = d.out + (size_t)vec * d.os;
    int row0 = ci * d.chunk;
    int rows = min(d.chunk, d.in_dim - row0);
    for (int t = tid; t < rows; t += TPB) {
        int idx = row0 + t;
        float v;
        if (d.op == 2) {
            int i = idx / d.aggdim, k = idx - i * d.aggdim;
            const int* nb = d.nb + i * 3;
            v = 0.25f * (x[i * d.aggdim + k] + x[nb[0] * d.aggdim + k] +
                         x[nb[1] * d.aggdim + k] + x[nb[2] * d.aggdim + k]);
        } else if (d.op == 3) {
            v = x[idx];
#pragma unroll
            for (int f = 1; f < 8; ++f) v = fmaxf(v, x[f * d.in_dim + idx]);
        } else {
            v = x[idx];
            if (d.op == 1) v = fmaxf(v, 0.f);
        }
        sx[t] = v;
    }
    __syncthreads();
    int j = tile * (TPB * 4) + tid * 4;
    if (j >= d.out_dim) return;
    const float* wp = d.W + (size_t)row0 * d.out_dim + j;
    float ax = 0.f, ay = 0.f, az = 0.f, aw = 0.f;
#pragma unroll 16
    for (int t = 0; t < rows; ++t) {
        f4 w = *(const f4*)wp;
        float xv = sx[t];
        ax = fmaf(xv, w[0], ax); ay = fmaf(xv, w[1], ay);
        az = fmaf(xv, w[2], az); aw = fmaf(xv, w[3], aw);
        wp += d.out_dim;
    }
    if (ci == 0 && d.bias) {
        ax += d.bias[j]; ay += d.bias[j + 1]; az += d.bias[j + 2]; aw += d.bias[j + 3];
    }
    unsafeAtomicAdd(&out[j + 0], ax);
    unsafeAtomicAdd(&out[j + 1], ay);
    unsafeAtomicAdd(&out[j + 2], az);
    unsafeAtomicAdd(&out[j + 3], aw);
}

// head: logits = relu(M3H2) @ m3_W3 + b3   (256 -> 40)
__global__ __launch_bounds__(64) void head_kernel(
    const float* __restrict__ x, const float* __restrict__ W,
    const float* __restrict__ b, float* __restrict__ out) {
    __shared__ float sx[256];
    int tid = threadIdx.x;
    for (int k = tid; k < 256; k += 64) sx[k] = fmaxf(x[k], 0.f);
    __syncthreads();
    if (tid < 40) {
        float a = b[tid];
        for (int k = 0; k < 256; ++k) a = fmaf(sx[k], W[k * 40 + tid], a);
        out[tid] = a;
    }
}

// ---------------------------------------------------------------------------
static Desc gemv_desc(const float* x, const float* W, float* out, const float* bias,
                      int in, int outd, int chunk, int op,
                      int nvec = 1, int xs = 0, int os = 0,
                      const int* nb = nullptr, int aggdim = 0) {
    Desc d{};
    d.x = x; d.W = W; d.out = out; d.bias = bias; d.nb = nb;
    d.in_dim = in; d.out_dim = outd; d.chunk = chunk;
    d.ntile = (outd + TPB * 4 - 1) / (TPB * 4);
    d.nchunk = (in + chunk - 1) / chunk;
    d.nvec = nvec; d.xs = xs; d.os = os;
    d.op = op; d.aggdim = aggdim;
    d.nblocks = d.ntile * d.nchunk * nvec;
    return d;
}
static Desc copy_desc(const float* src, float* dst, int n) {
    Desc d{};
    d.x = src; d.out = dst; d.in_dim = n; d.op = 4;
    d.nblocks = (n / 4 + TPB - 1) / TPB;
    return d;
}
static void mg1(hipStream_t s, Desc a) {
    Descs D{}; D.d[0] = a; D.nd = 1;
    mg_kernel<<<a.nblocks, TPB, 0, s>>>(D);
}
static void mg2(hipStream_t s, Desc a, Desc b) {
    Descs D{}; D.d[0] = a; D.d[1] = b; D.nd = 2;
    mg_kernel<<<a.nblocks + b.nblocks, TPB, 0, s>>>(D);
}
static void mg3(hipStream_t s, Desc a, Desc b, Desc c) {
    Descs D{}; D.d[0] = a; D.d[1] = b; D.d[2] = c; D.nd = 3;
    mg_kernel<<<a.nblocks + b.nblocks + c.nblocks, TPB, 0, s>>>(D);
}

extern "C" void kernel_launch(void* const* d_in, const int* in_sizes, int n_in,
                              void* d_out, int out_size, void* d_ws, size_t ws_size,
                              hipStream_t stream) {
    const float* center    = (const float*)d_in[0];
    const float* corner    = (const float*)d_in[1];
    const float* normal    = (const float*)d_in[2];
    const int*   neighbour = (const int*)  d_in[3];
    const float* sp_W1 = (const float*)d_in[4];
    const float* sp_b1 = (const float*)d_in[5];
    const float* sp_W2 = (const float*)d_in[6];
    const float* sp_b2 = (const float*)d_in[7];
    const float* frc_Wc = (const float*)d_in[8];
    const float* frc_bc = (const float*)d_in[9];
    const float* frc_W3 = (const float*)d_in[10];
    const float* frc_b3 = (const float*)d_in[11];
    const float* frc_W4 = (const float*)d_in[12];
    const float* frc_b4 = (const float*)d_in[13];
    const float* kc_kernel = (const float*)d_in[14];
    const float* st_W1 = (const float*)d_in[15];
    const float* st_b1 = (const float*)d_in[16];
    const float* st_W2 = (const float*)d_in[17];
    const float* st_b2 = (const float*)d_in[18];
    const float* c1_W1 = (const float*)d_in[19];
    const float* c1_b1 = (const float*)d_in[20];
    const float* c1_W2 = (const float*)d_in[21];
    const float* c1_b2 = (const float*)d_in[22];
    const float* a1_W3 = (const float*)d_in[23];
    const float* a1_b3 = (const float*)d_in[24];
    const float* a1_W4 = (const float*)d_in[25];
    const float* a1_b4 = (const float*)d_in[26];
    const float* c2_W1 = (const float*)d_in[27];
    const float* c2_b1 = (const float*)d_in[28];
    const float* c2_W2 = (const float*)d_in[29];
    const float* c2_b2 = (const float*)d_in[30];
    const float* a2_W3 = (const float*)d_in[31];
    const float* a2_b3 = (const float*)d_in[32];
    const float* a2_W4 = (const float*)d_in[33];
    const float* a2_b4 = (const float*)d_in[34];
    const float* nt_W1 = (const float*)d_in[35];
    const float* nt_b1 = (const float*)d_in[36];
    const float* nt_W2 = (const float*)d_in[37];
    const float* nt_b2 = (const float*)d_in[38];
    const float* m2_W1 = (const float*)d_in[39];
    const float* m2_b1 = (const float*)d_in[40];
    const float* m2_W2 = (const float*)d_in[41];
    const float* m2_b2 = (const float*)d_in[42];
    const float* m3_W1 = (const float*)d_in[43];
    const float* m3_b1 = (const float*)d_in[44];
    const float* m3_W2 = (const float*)d_in[45];
    const float* m3_b2 = (const float*)d_in[46];
    const float* m3_W3 = (const float*)d_in[47];
    const float* m3_b3 = (const float*)d_in[48];

    float* ws = (float*)d_ws;
    float* C1IN  = ws + 512;           // [Y(512) | Z(1048)]
    float* Z     = ws + 1024;
    float* C1H   = ws + 2072;
    float* OUT12 = ws + 3672;          // [out1 | out2]
    float* A1H   = ws + 7768;
    float* C2H   = ws + 11864;
    float* OUT34 = ws + 15960;         // [out3 | out4]
    float* A2H   = ws + 24152;
    float* NTH   = ws + 28248;
    float* OUT6  = ws + 36440;         // [out5 | out3c | out1c]
    float* M2H   = ws + 50776;
    float* HBUF  = ws + 58968;
    float* M3H1  = ws + 67160;
    float* M3H2  = ws + 67672;

    // L1: faces + spatial chain + zeroing
    stage1_kernel<<<44, TPB, 0, stream>>>(center, corner, normal,
        sp_W1, sp_b1, sp_W2, sp_b2, frc_Wc, frc_bc, frc_W3, frc_b3,
        frc_W4, frc_b4, kc_kernel, st_W1, st_b1, st_W2, st_b2, ws);

    // L2: c1_W1 (x=[y|z]) + a1_W3 (agg1 inline from Z)
    mg2(stream,
        gemv_desc(C1IN, c1_W1, C1H, c1_b1, 1560, 1600, 26, 0),
        gemv_desc(Z, a1_W3, A1H, a1_b3, 1048, 4096, 17, 2, 1, 0, 0, neighbour, 131));
    // L3: c1_W2 + a1_W4
    mg2(stream,
        gemv_desc(C1H, c1_W2, OUT12, c1_b2, 1600, 2048, 28, 1),
        gemv_desc(A1H, a1_W4, OUT12 + 2048, a1_b4, 4096, 2048, 64, 1));
    // L4: c2_W1 + a2_W3 (agg2 inline from out2)
    mg2(stream,
        gemv_desc(OUT12, c2_W1, C2H, c2_b1, 4096, 4096, 64, 0),
        gemv_desc(OUT12 + 2048, a2_W3, A2H, a2_b3, 2048, 4096, 32, 2, 1, 0, 0, neighbour, 256));
    // L5: c2_W2 + a2_W4 + copy out1 -> OUT6 tail
    mg3(stream,
        gemv_desc(C2H, c2_W2, OUT34, c2_b2, 4096, 4096, 64, 1),
        gemv_desc(A2H, a2_W4, OUT34 + 4096, a2_b4, 4096, 4096, 64, 1),
        copy_desc(OUT12, OUT6 + 12288, 2048));
    // L6: nt_W1 (8 faces) + copy out3 -> OUT6 mid
    mg2(stream,
        gemv_desc(OUT34, nt_W1, NTH, nt_b1, 1024, 1024, 64, 0, 8, 1024, 1024),
        copy_desc(OUT34, OUT6 + 8192, 4096));
    // L7: nt_W2 -> out5
    mg1(stream,
        gemv_desc(NTH, nt_W2, OUT6, nt_b2, 1024, 1024, 64, 1, 8, 1024, 1024));
    // L8: m2_W1
    mg1(stream, gemv_desc(OUT6, m2_W1, M2H, m2_b1, 14336, 8192, 448, 0));
    // L9: m2_W2
    mg1(stream, gemv_desc(M2H, m2_W2, HBUF, m2_b2, 8192, 8192, 256, 1));
    // L10: m3_W1 with inline maxpool over 8 faces
    mg1(stream, gemv_desc(HBUF, m3_W1, M3H1, m3_b1, 1024, 512, 16, 3));
    // L11: m3_W2
    mg1(stream, gemv_desc(M3H1, m3_W2, M3H2, m3_b2, 512, 256, 8, 1));
    // L12: head
    head_kernel<<<1, 64, 0, stream>>>(M3H2, m3_W3, m3_b3, (float*)d_out);
}